// Round 1
// 107.533 us; speedup vs baseline: 1.0811x; 1.0811x over previous
//
#include <hip/hip_runtime.h>
#include <stdint.h>

// ContrastiveLoss (SimCLR NT-Xent), B=4096, D=128, T=0.5
// loss = (1/2B) * sum_k log(denom_k)  -  (1/(B*T)) * sum_i dot(z_i, z_j_i)
//
// Round 2: sim is symmetric (sim = R R^T). Compute only upper-triangle
// 128x128 tiles (2080 blocks instead of 1024 full blocks => 0.52x MFMA+exp
// work). Off-diagonal tiles contribute row-sums to rowsum[rows] AND
// column-sums to rowsum[cols] (per-wave LDS accumulator, one global atomic
// per column per block). Diagonal mask (r==c) only in the 64 diagonal
// blocks. B-fragments software-pipelined (prefetch next col-tile into regs
// before the MFMA cluster) to cover L2 latency; 2080 x 128-thread blocks
// keep the whole grid resident (8 blocks/CU).

#define TEMP 0.5f
// exp(x/T) = exp2(x * log2(e)/T); T=0.5 -> scale = 2*log2(e)
#define EXP2_SCALE 2.885390081777927f

typedef __bf16 bf16_t;
typedef bf16_t bf16x8 __attribute__((ext_vector_type(8)));
typedef float floatx4 __attribute__((ext_vector_type(4)));

__device__ __forceinline__ unsigned short f32_to_bf16(float f) {
    union { float f; uint32_t u; } v; v.f = f;
    uint32_t u = v.u;
    uint32_t r = (u + 0x7FFFu + ((u >> 16) & 1u)) >> 16;  // RNE
    return (unsigned short)r;
}

__device__ __forceinline__ bf16x8 as_bf16x8(uint4 v) {
    union { uint4 u; bf16x8 b; } c; c.u = v; return c.b;
}

// ---------------------------------------------------------------------------
// Kernel 1: per-row L2 normalize, bf16 reps[2B][128]; pos[i] = dot(z_i,z_j).
// Also zeroes rowsum (8 floats per block) -> replaces the hipMemsetAsync
// dispatch.
// ---------------------------------------------------------------------------
__global__ __launch_bounds__(256) void norm_pos_kernel(
        const float* __restrict__ p1, const float* __restrict__ p2,
        unsigned short* __restrict__ reps, float* __restrict__ pos,
        float* __restrict__ rowsum, int B) {
    if (threadIdx.x < 8) {
        int z = blockIdx.x * 8 + threadIdx.x;
        if (z < 2 * B) rowsum[z] = 0.f;
    }

    int wave = threadIdx.x >> 6;
    int lane = threadIdx.x & 63;
    int i = blockIdx.x * 4 + wave;
    if (i >= B) return;

    const float2* r1 = (const float2*)(p1 + (size_t)i * 128);
    const float2* r2 = (const float2*)(p2 + (size_t)i * 128);
    float2 a = r1[lane];
    float2 b = r2[lane];
    float ss1 = a.x * a.x + a.y * a.y;
    float ss2 = b.x * b.x + b.y * b.y;
    float d   = a.x * b.x + a.y * b.y;
    #pragma unroll
    for (int off = 32; off > 0; off >>= 1) {
        ss1 += __shfl_xor(ss1, off);
        ss2 += __shfl_xor(ss2, off);
        d   += __shfl_xor(d,   off);
    }
    float rn1 = rsqrtf(fmaxf(ss1, 1e-24f));
    float rn2 = rsqrtf(fmaxf(ss2, 1e-24f));

    ushort2* z1 = (ushort2*)reps + (size_t)i * 64;
    ushort2* z2 = (ushort2*)reps + (size_t)(B + i) * 64;
    z1[lane] = make_ushort2(f32_to_bf16(a.x * rn1), f32_to_bf16(a.y * rn1));
    z2[lane] = make_ushort2(f32_to_bf16(b.x * rn2), f32_to_bf16(b.y * rn2));

    if (lane == 0) pos[i] = d * rn1 * rn2;
}

// ---------------------------------------------------------------------------
// Kernel 2: symmetric sim+exp. Block = 2 waves = 128x128 output tile at
// triangle coords (by, bx), bx >= by. Wave owns 64 rows as 4 A-tiles of 16
// rows in registers (16x16x32 bf16 MFMA, layout verified round 1). 8
// col-tiles per block; B-frags double-buffered in registers (prefetch ct+1
// before MFMAs of ct). Off-diag blocks also accumulate per-column sums
// (LDS, per-wave slot, no LDS atomics) and flush them to rowsum[cols] --
// that is the transposed half of the matrix, never computed explicitly.
// ---------------------------------------------------------------------------
__global__ __launch_bounds__(128) void simexp_kernel(
        const unsigned short* __restrict__ reps,
        float* __restrict__ rowsum, int nt) {
    const int tid  = threadIdx.x;
    const int wave = tid >> 6;
    const int lane = tid & 63;
    const int quad = lane >> 4;
    const int l16  = lane & 15;

    // linear block id -> upper-triangle (by, bx); row 'by' has nt-by tiles
    int rem = (int)blockIdx.x;
    int by = 0;
    while (rem >= nt - by) { rem -= nt - by; ++by; }
    const int bx = by + rem;
    const bool diag = (bx == by);

    const int rowWave = by * 128 + wave * 64;  // this wave's 64 rows
    const int colBase = bx * 128;              // this block's 128 cols

    const uint4* g = (const uint4*)reps;  // 16 uint4 per 256-B row

    __shared__ float lds_cs[2][128];  // per-wave column-sum accumulators
    if (!diag) {
        lds_cs[wave][lane]      = 0.f;
        lds_cs[wave][lane + 64] = 0.f;
        // no barrier needed: each wave touches only its own slot until the end
    }

    // A-fragments: 4 row-tiles x 4 k-steps (64 VGPRs), read once
    bf16x8 a[4][4];
    #pragma unroll
    for (int t = 0; t < 4; ++t)
        #pragma unroll
        for (int ks = 0; ks < 4; ++ks)
            a[t][ks] = as_bf16x8(g[(size_t)(rowWave + t * 16 + l16) * 16 + ks * 4 + quad]);

    float rs[4][4];
    #pragma unroll
    for (int t = 0; t < 4; ++t)
        #pragma unroll
        for (int r = 0; r < 4; ++r) rs[t][r] = 0.f;

    auto loadB = [&](bf16x8 (&dst)[4], int ct) {
        const size_t br = (size_t)(colBase + ct * 16 + l16) * 16;
        #pragma unroll
        for (int ks = 0; ks < 4; ++ks)
            dst[ks] = as_bf16x8(g[br + ks * 4 + quad]);
    };

    bf16x8 bcur[4], bnxt[4];
    loadB(bcur, 0);

    if (!diag) {
        #pragma unroll
        for (int ct = 0; ct < 8; ++ct) {
            if (ct < 7) loadB(bnxt, ct + 1);   // prefetch: hides L2 latency

            floatx4 acc[4];
            #pragma unroll
            for (int t = 0; t < 4; ++t) acc[t] = (floatx4){0.f, 0.f, 0.f, 0.f};
            #pragma unroll
            for (int ks = 0; ks < 4; ++ks)
                #pragma unroll
                for (int t = 0; t < 4; ++t)
                    acc[t] = __builtin_amdgcn_mfma_f32_16x16x32_bf16(a[t][ks], bcur[ks], acc[t], 0, 0, 0);

            float cs = 0.f;  // column sum for col = colBase + ct*16 + l16
            #pragma unroll
            for (int t = 0; t < 4; ++t)
                #pragma unroll
                for (int r = 0; r < 4; ++r) {
                    float e = exp2f(acc[t][r] * EXP2_SCALE);
                    rs[t][r] += e;
                    cs += e;
                }
            // reduce cs across the 4 quads (same l16) -> all lanes hold total
            cs += __shfl_xor(cs, 16);
            cs += __shfl_xor(cs, 32);
            if (lane < 16) lds_cs[wave][ct * 16 + lane] += cs;

            #pragma unroll
            for (int ks = 0; ks < 4; ++ks) bcur[ks] = bnxt[ks];
        }
    } else {
        #pragma unroll
        for (int ct = 0; ct < 8; ++ct) {
            if (ct < 7) loadB(bnxt, ct + 1);

            floatx4 acc[4];
            #pragma unroll
            for (int t = 0; t < 4; ++t) acc[t] = (floatx4){0.f, 0.f, 0.f, 0.f};
            #pragma unroll
            for (int ks = 0; ks < 4; ++ks)
                #pragma unroll
                for (int t = 0; t < 4; ++t)
                    acc[t] = __builtin_amdgcn_mfma_f32_16x16x32_bf16(a[t][ks], bcur[ks], acc[t], 0, 0, 0);

            const int c = colBase + ct * 16 + l16;
            #pragma unroll
            for (int t = 0; t < 4; ++t) {
                const int rb = rowWave + t * 16 + quad * 4;
                #pragma unroll
                for (int r = 0; r < 4; ++r) {
                    float e = (rb + r == c) ? 0.f : exp2f(acc[t][r] * EXP2_SCALE);
                    rs[t][r] += e;
                }
            }

            #pragma unroll
            for (int ks = 0; ks < 4; ++ks) bcur[ks] = bnxt[ks];
        }
    }

    // row-side: reduce rs across the 16 columns (l16 lanes) of each quad
    #pragma unroll
    for (int off = 1; off < 16; off <<= 1)
        #pragma unroll
        for (int t = 0; t < 4; ++t)
            #pragma unroll
            for (int r = 0; r < 4; ++r)
                rs[t][r] += __shfl_xor(rs[t][r], off);

    if (l16 == 0) {
        #pragma unroll
        for (int t = 0; t < 4; ++t)
            #pragma unroll
            for (int r = 0; r < 4; ++r)
                atomicAdd(&rowsum[rowWave + t * 16 + quad * 4 + r], rs[t][r]);
    }

    // col-side (transposed half): flush block column sums
    if (!diag) {
        __syncthreads();
        atomicAdd(&rowsum[colBase + tid], lds_cs[0][tid] + lds_cs[1][tid]);
    }
}

// ---------------------------------------------------------------------------
// Kernel 3: single block; out[0] = mean(log(rowsum)) - sum(pos)/(B*T).
// ---------------------------------------------------------------------------
__global__ __launch_bounds__(1024) void finalize_kernel(
        const float* __restrict__ rowsum, const float* __restrict__ pos,
        float* __restrict__ out, int N2, int B) {
    float v = 0.f;
    const float4* r4 = (const float4*)rowsum;
    const int n4 = N2 >> 2;
    for (int k = threadIdx.x; k < n4; k += 1024) {
        float4 x = r4[k];
        v += logf(x.x) + logf(x.y) + logf(x.z) + logf(x.w);
    }
    float p = 0.f;
    const float4* p4 = (const float4*)pos;
    const int b4 = B >> 2;
    for (int i = threadIdx.x; i < b4; i += 1024) {
        float4 x = p4[i];
        p += x.x + x.y + x.z + x.w;
    }
    float local = v * (1.0f / (float)N2) - p * (1.0f / ((float)B * TEMP));

    #pragma unroll
    for (int off = 32; off > 0; off >>= 1) local += __shfl_xor(local, off);

    __shared__ float wsum[16];
    int wave = threadIdx.x >> 6, lane = threadIdx.x & 63;
    if (lane == 0) wsum[wave] = local;
    __syncthreads();
    if (threadIdx.x == 0) {
        float s = 0.f;
        for (int i = 0; i < 16; ++i) s += wsum[i];
        out[0] = s;
    }
}

extern "C" void kernel_launch(void* const* d_in, const int* in_sizes, int n_in,
                              void* d_out, int out_size, void* d_ws, size_t ws_size,
                              hipStream_t stream) {
    const float* p1 = (const float*)d_in[0];
    const float* p2 = (const float*)d_in[1];
    float* out = (float*)d_out;

    const int B  = in_sizes[0] / 128;   // 4096
    const int N2 = 2 * B;               // 8192

    // ws layout: [reps bf16: N2*256 B][rowsum fp32: N2*4 B][pos fp32: B*4 B]
    unsigned short* reps = (unsigned short*)d_ws;
    float* rowsum = (float*)((char*)d_ws + (size_t)N2 * 256);
    float* pos    = rowsum + N2;

    norm_pos_kernel<<<dim3((B + 3) / 4), dim3(256), 0, stream>>>(p1, p2, reps, pos, rowsum, B);

    const int nt = N2 / 128;            // 64 row/col tiles
    const int nb = nt * (nt + 1) / 2;   // 2080 upper-triangle blocks
    simexp_kernel<<<dim3(nb), dim3(128), 0, stream>>>(reps, rowsum, nt);

    finalize_kernel<<<dim3(1), dim3(1024), 0, stream>>>(rowsum, pos, out, N2, B);
}

// Round 2
// 96.765 us; speedup vs baseline: 1.2014x; 1.1113x over previous
//
#include <hip/hip_runtime.h>
#include <stdint.h>

// ContrastiveLoss (SimCLR NT-Xent), B=4096, D=128, T=0.5
// loss = (1/2B) * sum_k log(denom_k)  -  (1/(B*T)) * sum_i dot(z_i, z_j_i)
//
// Round 3: symmetric triangle (128x128 tiles, 2080 blocks) kept from round 2.
// Fix for round-2 regression (VGPR 152 -> occupancy collapse): B-panels now
// staged through LDS with __builtin_amdgcn_global_load_lds (0 VGPR cost),
// double-buffered, stored in per-lane fragment order so ds_read_b128 is
// bank-conflict-free. Block = 4 waves x 32 rows each (A = 32 VGPR/wave);
// B shared by all 4 waves via LDS. m97-style 1-barrier-per-tile pipeline:
// stage ct+1 right after the barrier, loads fly under ct's MFMA+exp.

#define TEMP 0.5f
// exp(x/T) = exp2(x * log2(e)/T); T=0.5 -> scale = 2*log2(e)
#define EXP2_SCALE 2.885390081777927f

typedef __bf16 bf16_t;
typedef bf16_t bf16x8 __attribute__((ext_vector_type(8)));
typedef float floatx4 __attribute__((ext_vector_type(4)));

typedef __attribute__((address_space(3))) uint32_t lds_u32;
typedef const __attribute__((address_space(1))) uint32_t glb_u32;

__device__ __forceinline__ unsigned short f32_to_bf16(float f) {
    union { float f; uint32_t u; } v; v.f = f;
    uint32_t u = v.u;
    uint32_t r = (u + 0x7FFFu + ((u >> 16) & 1u)) >> 16;  // RNE
    return (unsigned short)r;
}

__device__ __forceinline__ bf16x8 as_bf16x8(uint4 v) {
    union { uint4 u; bf16x8 b; } c; c.u = v; return c.b;
}

// ---------------------------------------------------------------------------
// Kernel 1: per-row L2 normalize, bf16 reps[2B][128]; pos[i] = dot(z_i,z_j).
// Also zeroes rowsum (8 floats per block) -> no hipMemsetAsync dispatch.
// ---------------------------------------------------------------------------
__global__ __launch_bounds__(256) void norm_pos_kernel(
        const float* __restrict__ p1, const float* __restrict__ p2,
        unsigned short* __restrict__ reps, float* __restrict__ pos,
        float* __restrict__ rowsum, int B) {
    if (threadIdx.x < 8) {
        int z = blockIdx.x * 8 + threadIdx.x;
        if (z < 2 * B) rowsum[z] = 0.f;
    }

    int wave = threadIdx.x >> 6;
    int lane = threadIdx.x & 63;
    int i = blockIdx.x * 4 + wave;
    if (i >= B) return;

    const float2* r1 = (const float2*)(p1 + (size_t)i * 128);
    const float2* r2 = (const float2*)(p2 + (size_t)i * 128);
    float2 a = r1[lane];
    float2 b = r2[lane];
    float ss1 = a.x * a.x + a.y * a.y;
    float ss2 = b.x * b.x + b.y * b.y;
    float d   = a.x * b.x + a.y * b.y;
    #pragma unroll
    for (int off = 32; off > 0; off >>= 1) {
        ss1 += __shfl_xor(ss1, off);
        ss2 += __shfl_xor(ss2, off);
        d   += __shfl_xor(d,   off);
    }
    float rn1 = rsqrtf(fmaxf(ss1, 1e-24f));
    float rn2 = rsqrtf(fmaxf(ss2, 1e-24f));

    ushort2* z1 = (ushort2*)reps + (size_t)i * 64;
    ushort2* z2 = (ushort2*)reps + (size_t)(B + i) * 64;
    z1[lane] = make_ushort2(f32_to_bf16(a.x * rn1), f32_to_bf16(a.y * rn1));
    z2[lane] = make_ushort2(f32_to_bf16(b.x * rn2), f32_to_bf16(b.y * rn2));

    if (lane == 0) pos[i] = d * rn1 * rn2;
}

// ---------------------------------------------------------------------------
// Kernel 2: symmetric sim+exp, LDS-pipelined.
// Block = 4 waves = 128x128 tile at triangle coords (by, bx), bx >= by.
// Wave w owns rows by*128 + w*32 .. +32 as 2 A-tiles in registers
// (16x16x32 bf16 MFMA, fragment layout verified in round 0).
// B: 8 col-tiles of 16 cols; each 4 KB panel staged via global_load_lds into
// LDS *in per-lane fragment order* (slot = ks*1024B + lane*16B), so the
// read back is 4x ds_read_b128 with zero bank conflicts. Double-buffered:
// stage(ct+1) issued right after the barrier, flies under ct's MFMA+exp;
// __syncthreads()'s implicit vmcnt(0) publishes the buffer.
// Off-diag tiles also accumulate per-column sums (transposed half of sim,
// never computed explicitly) in per-wave LDS slots, flushed once per block.
// ---------------------------------------------------------------------------
__global__ __launch_bounds__(256) void simexp_kernel(
        const unsigned short* __restrict__ reps,
        float* __restrict__ rowsum, int nt) {
    const int tid  = threadIdx.x;
    const int wave = tid >> 6;
    const int lane = tid & 63;
    const int quad = lane >> 4;
    const int l16  = lane & 15;

    // linear block id -> upper-triangle (by, bx); row 'by' has nt-by tiles
    int rem = (int)blockIdx.x;
    int by = 0;
    while (rem >= nt - by) { rem -= nt - by; ++by; }
    const int bx = by + rem;
    const bool diag = (bx == by);

    const int rowWave = by * 128 + wave * 32;  // this wave's 32 rows
    const int colBase = bx * 128;              // this block's 128 cols

    const uint4* g = (const uint4*)reps;  // 16 uint4 per 256-B row

    __shared__ __align__(16) unsigned short bbuf[2][2048];  // 2 x 4 KB B panels
    __shared__ float lds_cs[4][128];                        // per-wave col sums

    lds_cs[wave][lane]      = 0.f;
    lds_cs[wave][lane + 64] = 0.f;
    // no barrier needed: each wave touches only its own slot until the end

    // A-fragments: 2 row-tiles x 4 k-steps (32 VGPRs), read once from L2
    bf16x8 a[2][4];
    #pragma unroll
    for (int t = 0; t < 2; ++t)
        #pragma unroll
        for (int ks = 0; ks < 4; ++ks)
            a[t][ks] = as_bf16x8(g[(size_t)(rowWave + t * 16 + l16) * 16 + ks * 4 + quad]);

    float rs[2][4];
    #pragma unroll
    for (int t = 0; t < 2; ++t)
        #pragma unroll
        for (int r = 0; r < 4; ++r) rs[t][r] = 0.f;

    // stage one 16-col B panel (4 KB) into bbuf[buf], per-lane fragment order.
    // thread tid stages fragment idx=tid: ks=idx>>6, frag-lane=idx&63.
    // LDS dest = bbuf[buf] + tid*16B  (wave-uniform base + lane*16: OK for
    // global_load_lds); global src = the bytes fragment (ks, flane) reads.
    const int s_ks  = tid >> 6;
    const int s_fl  = tid & 63;
    const int s_fq  = s_fl >> 4;
    const int s_f16 = s_fl & 15;
    auto stage = [&](int buf, int ct) {
        const unsigned short* src = reps
            + (size_t)(colBase + ct * 16 + s_f16) * 128 + s_ks * 32 + s_fq * 8;
        __builtin_amdgcn_global_load_lds(
            (glb_u32*)src, (lds_u32*)&bbuf[buf][tid * 8], 16, 0, 0);
    };

    stage(0, 0);  // prologue
    int cur = 0;

    #pragma unroll 1
    for (int ct = 0; ct < 8; ++ct) {
        __syncthreads();  // implicit vmcnt(0): bbuf[cur] staged for all waves
        if (ct < 7) stage(cur ^ 1, ct + 1);  // loads fly under compute below

        bf16x8 b[4];
        #pragma unroll
        for (int ks = 0; ks < 4; ++ks)
            b[ks] = *(const bf16x8*)&bbuf[cur][ks * 512 + lane * 8];

        floatx4 acc[2];
        #pragma unroll
        for (int t = 0; t < 2; ++t) acc[t] = (floatx4){0.f, 0.f, 0.f, 0.f};
        #pragma unroll
        for (int ks = 0; ks < 4; ++ks)
            #pragma unroll
            for (int t = 0; t < 2; ++t)
                acc[t] = __builtin_amdgcn_mfma_f32_16x16x32_bf16(a[t][ks], b[ks], acc[t], 0, 0, 0);

        const int c = colBase + ct * 16 + l16;  // this lane's output column
        if (!diag) {
            float cs = 0.f;
            #pragma unroll
            for (int t = 0; t < 2; ++t)
                #pragma unroll
                for (int r = 0; r < 4; ++r) {
                    float e = exp2f(acc[t][r] * EXP2_SCALE);
                    rs[t][r] += e;
                    cs += e;
                }
            // reduce cs across the 4 quads (same l16) -> 16 col sums
            cs += __shfl_xor(cs, 16);
            cs += __shfl_xor(cs, 32);
            if (lane < 16) lds_cs[wave][ct * 16 + lane] += cs;
        } else {
            #pragma unroll
            for (int t = 0; t < 2; ++t) {
                const int rb = rowWave + t * 16 + quad * 4;
                #pragma unroll
                for (int r = 0; r < 4; ++r) {
                    float e = (rb + r == c) ? 0.f : exp2f(acc[t][r] * EXP2_SCALE);
                    rs[t][r] += e;
                }
            }
        }
        cur ^= 1;
    }

    // row-side: reduce rs across the 16 columns (l16 lanes) of each quad
    #pragma unroll
    for (int off = 1; off < 16; off <<= 1)
        #pragma unroll
        for (int t = 0; t < 2; ++t)
            #pragma unroll
            for (int r = 0; r < 4; ++r)
                rs[t][r] += __shfl_xor(rs[t][r], off);

    if (l16 == 0) {
        #pragma unroll
        for (int t = 0; t < 2; ++t)
            #pragma unroll
            for (int r = 0; r < 4; ++r)
                atomicAdd(&rowsum[rowWave + t * 16 + quad * 4 + r], rs[t][r]);
    }

    // col-side (transposed half): flush block column sums
    if (!diag) {
        __syncthreads();
        if (tid < 128)
            atomicAdd(&rowsum[colBase + tid],
                      lds_cs[0][tid] + lds_cs[1][tid] + lds_cs[2][tid] + lds_cs[3][tid]);
    }
}

// ---------------------------------------------------------------------------
// Kernel 3: single block; out[0] = mean(log(rowsum)) - sum(pos)/(B*T).
// ---------------------------------------------------------------------------
__global__ __launch_bounds__(1024) void finalize_kernel(
        const float* __restrict__ rowsum, const float* __restrict__ pos,
        float* __restrict__ out, int N2, int B) {
    float v = 0.f;
    const float4* r4 = (const float4*)rowsum;
    const int n4 = N2 >> 2;
    for (int k = threadIdx.x; k < n4; k += 1024) {
        float4 x = r4[k];
        v += logf(x.x) + logf(x.y) + logf(x.z) + logf(x.w);
    }
    float p = 0.f;
    const float4* p4 = (const float4*)pos;
    const int b4 = B >> 2;
    for (int i = threadIdx.x; i < b4; i += 1024) {
        float4 x = p4[i];
        p += x.x + x.y + x.z + x.w;
    }
    float local = v * (1.0f / (float)N2) - p * (1.0f / ((float)B * TEMP));

    #pragma unroll
    for (int off = 32; off > 0; off >>= 1) local += __shfl_xor(local, off);

    __shared__ float wsum[16];
    int wave = threadIdx.x >> 6, lane = threadIdx.x & 63;
    if (lane == 0) wsum[wave] = local;
    __syncthreads();
    if (threadIdx.x == 0) {
        float s = 0.f;
        for (int i = 0; i < 16; ++i) s += wsum[i];
        out[0] = s;
    }
}

extern "C" void kernel_launch(void* const* d_in, const int* in_sizes, int n_in,
                              void* d_out, int out_size, void* d_ws, size_t ws_size,
                              hipStream_t stream) {
    const float* p1 = (const float*)d_in[0];
    const float* p2 = (const float*)d_in[1];
    float* out = (float*)d_out;

    const int B  = in_sizes[0] / 128;   // 4096
    const int N2 = 2 * B;               // 8192

    // ws layout: [reps bf16: N2*256 B][rowsum fp32: N2*4 B][pos fp32: B*4 B]
    unsigned short* reps = (unsigned short*)d_ws;
    float* rowsum = (float*)((char*)d_ws + (size_t)N2 * 256);
    float* pos    = rowsum + N2;

    norm_pos_kernel<<<dim3((B + 3) / 4), dim3(256), 0, stream>>>(p1, p2, reps, pos, rowsum, B);

    const int nt = N2 / 128;            // 64 row/col tiles
    const int nb = nt * (nt + 1) / 2;   // 2080 upper-triangle blocks
    simexp_kernel<<<dim3(nb), dim3(256), 0, stream>>>(reps, rowsum, nt);

    finalize_kernel<<<dim3(1), dim3(1024), 0, stream>>>(rowsum, pos, out, N2, B);
}

// Round 3
// 91.507 us; speedup vs baseline: 1.2704x; 1.0574x over previous
//
#include <hip/hip_runtime.h>
#include <stdint.h>

// ContrastiveLoss (SimCLR NT-Xent), B=4096, D=128, T=0.5
// loss = (1/2B) * sum_k log(denom_k)  -  (1/(B*T)) * sum_i dot(z_i, z_j_i)
//
// Round 4: symmetric triangle (128x128 tiles, 2080 blocks) kept.
// Fix for round-3's residual latency: round-3 barriered 8x per block around
// 4 KB panels (each __syncthreads = vmcnt(0) drain, prefetch distance ~200cyc
// vs ~400cyc L2 latency). The whole 128-col B strip is only 32 KB: stage it
// ONCE per block via global_load_lds (fragment order, ds_read_b128
// conflict-free), ONE barrier, then all 8 col-tiles run back-to-back with no
// further syncs. A-frag global loads fly concurrently with the staging.
// 4 blocks/CU (34 KB LDS) hide each other's startup.

#define TEMP 0.5f
// exp(x/T) = exp2(x * log2(e)/T); T=0.5 -> scale = 2*log2(e)
#define EXP2_SCALE 2.885390081777927f

typedef __bf16 bf16_t;
typedef bf16_t bf16x8 __attribute__((ext_vector_type(8)));
typedef float floatx4 __attribute__((ext_vector_type(4)));

typedef __attribute__((address_space(3))) uint32_t lds_u32;
typedef const __attribute__((address_space(1))) uint32_t glb_u32;

__device__ __forceinline__ unsigned short f32_to_bf16(float f) {
    union { float f; uint32_t u; } v; v.f = f;
    uint32_t u = v.u;
    uint32_t r = (u + 0x7FFFu + ((u >> 16) & 1u)) >> 16;  // RNE
    return (unsigned short)r;
}

__device__ __forceinline__ bf16x8 as_bf16x8(uint4 v) {
    union { uint4 u; bf16x8 b; } c; c.u = v; return c.b;
}

// ---------------------------------------------------------------------------
// Kernel 1: per-row L2 normalize, bf16 reps[2B][128]; pos[i] = dot(z_i,z_j).
// float4 loads: each wave handles 2 rows (lanes 0-31 / 32-63), 8 rows/block.
// Also zeroes rowsum (16 floats per block) -> no hipMemsetAsync dispatch.
// ---------------------------------------------------------------------------
__global__ __launch_bounds__(256) void norm_pos_kernel(
        const float* __restrict__ p1, const float* __restrict__ p2,
        unsigned short* __restrict__ reps, float* __restrict__ pos,
        float* __restrict__ rowsum, int B) {
    if (threadIdx.x < 16) {
        int z = blockIdx.x * 16 + threadIdx.x;
        if (z < 2 * B) rowsum[z] = 0.f;
    }

    const int wave = threadIdx.x >> 6;
    const int lane = threadIdx.x & 63;
    const int half = lane >> 5;   // which of the wave's 2 rows
    const int h    = lane & 31;   // 32 lanes x float4 = 128 floats = one row
    const int i = blockIdx.x * 8 + wave * 2 + half;
    if (i >= B) return;

    float4 a = ((const float4*)(p1 + (size_t)i * 128))[h];
    float4 b = ((const float4*)(p2 + (size_t)i * 128))[h];
    float ss1 = a.x * a.x + a.y * a.y + a.z * a.z + a.w * a.w;
    float ss2 = b.x * b.x + b.y * b.y + b.z * b.z + b.w * b.w;
    float d   = a.x * b.x + a.y * b.y + a.z * b.z + a.w * b.w;
    #pragma unroll
    for (int off = 16; off > 0; off >>= 1) {   // stays within each 32-half
        ss1 += __shfl_xor(ss1, off);
        ss2 += __shfl_xor(ss2, off);
        d   += __shfl_xor(d,   off);
    }
    float rn1 = rsqrtf(fmaxf(ss1, 1e-24f));
    float rn2 = rsqrtf(fmaxf(ss2, 1e-24f));

    ((ushort4*)reps)[(size_t)i * 32 + h] = make_ushort4(
        f32_to_bf16(a.x * rn1), f32_to_bf16(a.y * rn1),
        f32_to_bf16(a.z * rn1), f32_to_bf16(a.w * rn1));
    ((ushort4*)reps)[(size_t)(B + i) * 32 + h] = make_ushort4(
        f32_to_bf16(b.x * rn2), f32_to_bf16(b.y * rn2),
        f32_to_bf16(b.z * rn2), f32_to_bf16(b.w * rn2));

    if (h == 0) pos[i] = d * rn1 * rn2;
}

// ---------------------------------------------------------------------------
// Kernel 2: symmetric sim+exp, single-stage LDS.
// Block = 4 waves = 128x128 tile at triangle coords (by, bx), bx >= by.
// Wave w owns rows by*128 + w*32 as 2 A-tiles in registers (16x16x32 bf16
// MFMA, fragment layout verified round 0). Entire 128-col B strip (32 KB, 8
// panels of 16 cols) staged once via global_load_lds in per-lane fragment
// order (panel ct at ct*4096 + ks*1024 + flane*16 bytes -> ds_read_b128 with
// zero bank conflicts). One __syncthreads (implicit vmcnt(0)) then 8
// col-tiles with no further barriers. Off-diag tiles accumulate per-column
// sums (transposed half of sim) in per-wave LDS slots, flushed once.
// ---------------------------------------------------------------------------
__global__ __launch_bounds__(256) void simexp_kernel(
        const unsigned short* __restrict__ reps,
        float* __restrict__ rowsum, int nt) {
    const int tid  = threadIdx.x;
    const int wave = tid >> 6;
    const int lane = tid & 63;
    const int quad = lane >> 4;
    const int l16  = lane & 15;

    // linear block id -> upper-triangle (by, bx); row 'by' has nt-by tiles
    int rem = (int)blockIdx.x;
    int by = 0;
    while (rem >= nt - by) { rem -= nt - by; ++by; }
    const int bx = by + rem;
    const bool diag = (bx == by);

    const int rowWave = by * 128 + wave * 32;  // this wave's 32 rows
    const int colBase = bx * 128;              // this block's 128 cols

    const uint4* g = (const uint4*)reps;  // 16 uint4 per 256-B row

    __shared__ __align__(16) unsigned short bbuf[8][2048];  // 32 KB B strip
    __shared__ float lds_cs[4][128];                        // per-wave col sums

    lds_cs[wave][lane]      = 0.f;
    lds_cs[wave][lane + 64] = 0.f;
    // no barrier needed: each wave touches only its own slot until the end

    // stage all 8 panels; thread tid stages fragment (ks=tid>>6, fl=tid&63)
    // of each panel. LDS dest = panel base + tid*16 (wave-uniform + lane*16).
    const int s_ks  = tid >> 6;
    const int s_fl  = tid & 63;
    const int s_fq  = s_fl >> 4;
    const int s_f16 = s_fl & 15;
    #pragma unroll
    for (int ct = 0; ct < 8; ++ct) {
        const unsigned short* src = reps
            + (size_t)(colBase + ct * 16 + s_f16) * 128 + s_ks * 32 + s_fq * 8;
        __builtin_amdgcn_global_load_lds(
            (glb_u32*)src, (lds_u32*)&bbuf[ct][tid * 8], 16, 0, 0);
    }

    // A-fragments: 2 row-tiles x 4 k-steps (32 VGPRs); these global loads
    // overlap with the LDS staging above.
    bf16x8 a[2][4];
    #pragma unroll
    for (int t = 0; t < 2; ++t)
        #pragma unroll
        for (int ks = 0; ks < 4; ++ks)
            a[t][ks] = as_bf16x8(g[(size_t)(rowWave + t * 16 + l16) * 16 + ks * 4 + quad]);

    float rs[2][4];
    #pragma unroll
    for (int t = 0; t < 2; ++t)
        #pragma unroll
        for (int r = 0; r < 4; ++r) rs[t][r] = 0.f;

    __syncthreads();  // implicit vmcnt(0): whole B strip (and A) resident

    #pragma unroll 2
    for (int ct = 0; ct < 8; ++ct) {
        bf16x8 b[4];
        #pragma unroll
        for (int ks = 0; ks < 4; ++ks)
            b[ks] = *(const bf16x8*)&bbuf[ct][ks * 512 + lane * 8];

        floatx4 acc[2];
        #pragma unroll
        for (int t = 0; t < 2; ++t) acc[t] = (floatx4){0.f, 0.f, 0.f, 0.f};
        #pragma unroll
        for (int ks = 0; ks < 4; ++ks)
            #pragma unroll
            for (int t = 0; t < 2; ++t)
                acc[t] = __builtin_amdgcn_mfma_f32_16x16x32_bf16(a[t][ks], b[ks], acc[t], 0, 0, 0);

        const int c = colBase + ct * 16 + l16;  // this lane's output column
        if (!diag) {
            float cs = 0.f;
            #pragma unroll
            for (int t = 0; t < 2; ++t)
                #pragma unroll
                for (int r = 0; r < 4; ++r) {
                    float e = exp2f(acc[t][r] * EXP2_SCALE);
                    rs[t][r] += e;
                    cs += e;
                }
            // reduce cs across the 4 quads (same l16) -> 16 col sums
            cs += __shfl_xor(cs, 16);
            cs += __shfl_xor(cs, 32);
            if (lane < 16) lds_cs[wave][ct * 16 + lane] += cs;
        } else {
            #pragma unroll
            for (int t = 0; t < 2; ++t) {
                const int rb = rowWave + t * 16 + quad * 4;
                #pragma unroll
                for (int r = 0; r < 4; ++r) {
                    float e = (rb + r == c) ? 0.f : exp2f(acc[t][r] * EXP2_SCALE);
                    rs[t][r] += e;
                }
            }
        }
    }

    // row-side: reduce rs across the 16 columns (l16 lanes) of each quad
    #pragma unroll
    for (int off = 1; off < 16; off <<= 1)
        #pragma unroll
        for (int t = 0; t < 2; ++t)
            #pragma unroll
            for (int r = 0; r < 4; ++r)
                rs[t][r] += __shfl_xor(rs[t][r], off);

    if (l16 == 0) {
        #pragma unroll
        for (int t = 0; t < 2; ++t)
            #pragma unroll
            for (int r = 0; r < 4; ++r)
                atomicAdd(&rowsum[rowWave + t * 16 + quad * 4 + r], rs[t][r]);
    }

    // col-side (transposed half): flush block column sums
    if (!diag) {
        __syncthreads();
        if (tid < 128)
            atomicAdd(&rowsum[colBase + tid],
                      lds_cs[0][tid] + lds_cs[1][tid] + lds_cs[2][tid] + lds_cs[3][tid]);
    }
}

// ---------------------------------------------------------------------------
// Kernel 3: single block; out[0] = mean(log(rowsum)) - sum(pos)/(B*T).
// ---------------------------------------------------------------------------
__global__ __launch_bounds__(1024) void finalize_kernel(
        const float* __restrict__ rowsum, const float* __restrict__ pos,
        float* __restrict__ out, int N2, int B) {
    float v = 0.f;
    const float4* r4 = (const float4*)rowsum;
    const int n4 = N2 >> 2;
    for (int k = threadIdx.x; k < n4; k += 1024) {
        float4 x = r4[k];
        v += logf(x.x) + logf(x.y) + logf(x.z) + logf(x.w);
    }
    float p = 0.f;
    const float4* p4 = (const float4*)pos;
    const int b4 = B >> 2;
    for (int i = threadIdx.x; i < b4; i += 1024) {
        float4 x = p4[i];
        p += x.x + x.y + x.z + x.w;
    }
    float local = v * (1.0f / (float)N2) - p * (1.0f / ((float)B * TEMP));

    #pragma unroll
    for (int off = 32; off > 0; off >>= 1) local += __shfl_xor(local, off);

    __shared__ float wsum[16];
    int wave = threadIdx.x >> 6, lane = threadIdx.x & 63;
    if (lane == 0) wsum[wave] = local;
    __syncthreads();
    if (threadIdx.x == 0) {
        float s = 0.f;
        for (int i = 0; i < 16; ++i) s += wsum[i];
        out[0] = s;
    }
}

extern "C" void kernel_launch(void* const* d_in, const int* in_sizes, int n_in,
                              void* d_out, int out_size, void* d_ws, size_t ws_size,
                              hipStream_t stream) {
    const float* p1 = (const float*)d_in[0];
    const float* p2 = (const float*)d_in[1];
    float* out = (float*)d_out;

    const int B  = in_sizes[0] / 128;   // 4096
    const int N2 = 2 * B;               // 8192

    // ws layout: [reps bf16: N2*256 B][rowsum fp32: N2*4 B][pos fp32: B*4 B]
    unsigned short* reps = (unsigned short*)d_ws;
    float* rowsum = (float*)((char*)d_ws + (size_t)N2 * 256);
    float* pos    = rowsum + N2;

    norm_pos_kernel<<<dim3((B + 7) / 8), dim3(256), 0, stream>>>(p1, p2, reps, pos, rowsum, B);

    const int nt = N2 / 128;            // 64 row/col tiles
    const int nb = nt * (nt + 1) / 2;   // 2080 upper-triangle blocks
    simexp_kernel<<<dim3(nb), dim3(256), 0, stream>>>(reps, rowsum, nt);

    finalize_kernel<<<dim3(1), dim3(1024), 0, stream>>>(rowsum, pos, out, N2, B);
}